// Round 10
// baseline (1247.240 us; speedup 1.0000x reference)
//
#include <hip/hip_runtime.h>
#include <math.h>

#define BS   256
#define NN   255
#define DIM  128
#define GAMMA 0.07
#define NUM_ITERS 1000

typedef float v2f __attribute__((ext_vector_type(2)));

__device__ __forceinline__ double wred_d(double v) {
  #pragma unroll
  for (int k = 1; k < 64; k <<= 1) v += __shfl_xor(v, k, 64);
  return v;
}
__device__ __forceinline__ int wred_i(int v) {
  #pragma unroll
  for (int k = 1; k < 64; k <<= 1) v += __shfl_xor(v, k, 64);
  return v;
}

// lane-uniform float readlane
__device__ __forceinline__ float RLF(float v, int lane) {
  return __int_as_float(__builtin_amdgcn_readlane(__float_as_int(v), lane));
}

// DPP wave64 sum -> total broadcast via readlane(63). VALU-only.
template <int CTRL, int RMASK>
__device__ __forceinline__ float dpp_add(float x) {
  int t = __builtin_amdgcn_update_dpp(0, __float_as_int(x), CTRL, RMASK, 0xf, true);
  return x + __int_as_float(t);
}
__device__ __forceinline__ float wred64_dpp(float x) {
  x = dpp_add<0x111, 0xf>(x);   // row_shr:1
  x = dpp_add<0x112, 0xf>(x);   // row_shr:2
  x = dpp_add<0x114, 0xf>(x);   // row_shr:4
  x = dpp_add<0x118, 0xf>(x);   // row_shr:8
  x = dpp_add<0x142, 0xa>(x);   // row_bcast:15
  x = dpp_add<0x143, 0xc>(x);   // row_bcast:31; lane63 = total
  return RLF(x, 63);
}

// fast reciprocal-sqrt: v_rsq_f32 + one Newton step (~0.5 ulp)
__device__ __forceinline__ float rsq_nr(float x) {
  float r;
  asm("v_rsq_f32 %0, %1" : "=v"(r) : "v"(x));
  r = r * (1.5f - 0.5f * x * r * r);
  return r;
}

// packed dual-fp32 FMA (VOP3P): acc.lo += k.lo*y.lo; acc.hi += k.hi*y.hi
__device__ __forceinline__ void pk_fma(v2f& acc, const v2f& k, const v2f& y) {
  asm("v_pk_fma_f32 %0, %1, %2, %0" : "+v"(acc) : "v"(k), "v"(y));
}

// packed dual-fp32 add (VOP3P): component-wise IEEE add -> bit-exact
__device__ __forceinline__ v2f pk_add(v2f a, v2f b) {
  v2f d;
  asm("v_pk_add_f32 %0, %1, %2" : "=v"(d) : "v"(a), "v"(b));
  return d;
}

// ---------------- kernel 1: normalized features, stored transposed fp64 ----------------
__global__ void k_ftr(const float* __restrict__ z, double* __restrict__ ftrT) {
  int b = blockIdx.x;
  int d = threadIdx.x;
  double z0 = (double)z[b * 256 + d];
  double z1 = (double)z[b * 256 + 128 + d];
  double n = sqrt(z0 * z0 + z1 * z1);
  n = fmax(n, 1e-12);
  ftrT[d * 512 + b]       = z0 / n;
  ftrT[d * 512 + 256 + b] = z1 / n;
}

// ---------------- kernel 2: K = exp(-gamma * dist), fp64 math, fp32 store ----------------
__global__ void k_K(const double* __restrict__ ftrT, float* __restrict__ K,
                    double* __restrict__ pk_knt, double* __restrict__ pos_arr) {
  int i = blockIdx.x;
  int t = threadIdx.x;
  __shared__ double rowi[DIM];
  __shared__ double redd[4];
  if (t < DIM) rowi[t] = ftrT[t * 512 + i];
  __syncthreads();
  double xn = 0.0;
  #pragma unroll 8
  for (int d = 0; d < DIM; ++d) xn += rowi[d] * rowi[d];

  double knt_part = 0.0;
  #pragma unroll
  for (int h = 0; h < 2; ++h) {
    int j = t + h * 256;
    double dot = 0.0, sq = 0.0;
    #pragma unroll 8
    for (int d = 0; d < DIM; ++d) {
      double f = ftrT[d * 512 + j];
      dot += rowi[d] * f;
      sq  += f * f;
    }
    double dist = xn + sq - 2.0 * dot;
    double kv = exp(-GAMMA * dist);
    K[i * 512 + j] = (float)kv;
    if (h == 1) {
      if (j == 256 + i) pos_arr[i] = kv;
      else knt_part += kv;
    }
  }
  double w = wred_d(knt_part);
  if ((t & 63) == 0) redd[t >> 6] = w;
  __syncthreads();
  if (t == 0) pk_knt[i] = redd[0] + redd[1] + redd[2] + redd[3];
}

// ---- R15/R22-exact band matvec: 8 bcast b128 y-reads + 64 pk_fma ----
__device__ __forceinline__ float4 matvec8(const v2f* kq, const float* ybase) {
  const float4* yb = (const float4*)ybase;
  v2f a0 = {0.f, 0.f}, a1 = {0.f, 0.f}, a2 = {0.f, 0.f}, a3 = {0.f, 0.f};
  #pragma unroll
  for (int jj = 0; jj < 8; ++jj) {
    float4 yq = yb[jj];
    v2f ylo = {yq.x, yq.y};
    v2f yhi = {yq.z, yq.w};
    pk_fma(a0, kq[2 * jj],      ylo); pk_fma(a0, kq[2 * jj + 1],      yhi);
    pk_fma(a1, kq[16 + 2 * jj], ylo); pk_fma(a1, kq[16 + 2 * jj + 1], yhi);
    pk_fma(a2, kq[32 + 2 * jj], ylo); pk_fma(a2, kq[32 + 2 * jj + 1], yhi);
    pk_fma(a3, kq[48 + 2 * jj], ylo); pk_fma(a3, kq[48 + 2 * jj + 1], yhi);
  }
  float4 r;
  r.x = a0.x + a0.y; r.y = a1.x + a1.y; r.z = a2.x + a2.y; r.w = a3.x + a3.y;
  return r;
}

// ---- R22-exact phase B, owner band OWN kept in registers (same bits,
// same pk_add pairing regardless of OWN) ----
template <int OWN>
__device__ __forceinline__ void phase_b(
    const float (*part)[BS], const float* qown,
    float* al, float* ap, float* yv, const float* kv, const float* rm2,
    int l, int rq, int rc, float beta, float* ytil) {
  // S from owner wave's replicated yv regs (R22-validated bit-exact)
  float Sv = wred64_dpp((yv[0] + yv[1]) + (yv[2] + yv[3]));
  float4 q[8];
  #pragma unroll
  for (int m = 0; m < 8; ++m) {
    if (m == OWN) { q[m].x = qown[0]; q[m].y = qown[1]; q[m].z = qown[2]; q[m].w = qown[3]; }
    else q[m] = *(const float4*)&part[m][4 * l];
  }
  // pk-packed pairwise tree: identical pairing/order as R15's add4 tree
  v2f s01l = pk_add((v2f){q[0].x, q[0].y}, (v2f){q[1].x, q[1].y});
  v2f s01h = pk_add((v2f){q[0].z, q[0].w}, (v2f){q[1].z, q[1].w});
  v2f s23l = pk_add((v2f){q[2].x, q[2].y}, (v2f){q[3].x, q[3].y});
  v2f s23h = pk_add((v2f){q[2].z, q[2].w}, (v2f){q[3].z, q[3].w});
  v2f s45l = pk_add((v2f){q[4].x, q[4].y}, (v2f){q[5].x, q[5].y});
  v2f s45h = pk_add((v2f){q[4].z, q[4].w}, (v2f){q[5].z, q[5].w});
  v2f s67l = pk_add((v2f){q[6].x, q[6].y}, (v2f){q[7].x, q[7].y});
  v2f s67h = pk_add((v2f){q[6].z, q[6].w}, (v2f){q[7].z, q[7].w});
  v2f sAl = pk_add(s01l, s23l);
  v2f sAh = pk_add(s01h, s23h);
  v2f sBl = pk_add(s45l, s67l);
  v2f sBh = pk_add(s45h, s67h);
  v2f gAl = pk_add(sAl, sBl);
  v2f gAh = pk_add(sAh, sBh);
  float4 gA = {gAl.x, gAl.y, gAh.x, gAh.y};
  // gr = gA at column r (uniform rc select + readlane)
  float grv = (rc == 0) ? gA.x : (rc == 1) ? gA.y : (rc == 2) ? gA.z : gA.w;
  float gr = RLF(grv, rq);
  // a==r col: kv=rm2=yv=0 and gA==gr -> g = 0 exactly
  float g[4];
  g[0] = (gA.x - gr) - rm2[0] + kv[0] * Sv + 0.1f * yv[0];
  g[1] = (gA.y - gr) - rm2[1] + kv[1] * Sv + 0.1f * yv[1];
  g[2] = (gA.z - gr) - rm2[2] + kv[2] * Sv + 0.1f * yv[2];
  g[3] = (gA.w - gr) - rm2[3] + kv[3] * Sv + 0.1f * yv[3];
  float n2 = wred64_dpp((g[0] * g[0] + g[1] * g[1]) + (g[2] * g[2] + g[3] * g[3]));
  float sinv = 0.001f * rsq_nr(n2);
  #pragma unroll
  for (int k = 0; k < 4; ++k) {
    float na = fminf(fmaxf(fmaf(-sinv, g[k], yv[k]), 0.f), 1.f);
    ap[k] = al[k];
    al[k] = na;
    yv[k] = fmaf(beta, na - ap[k], na);
  }
  float4 y4 = {yv[0], yv[1], yv[2], yv[3]};
  *(float4*)&ytil[4 * l] = y4;                 // one b128, conflict-free
}

// ---------------- kernel 3: per-batch PGD — R24: dual-problem pipelined block ----------------
// K is IDENTICAL for all problems -> one block shares kq across TWO problems
// (rA=2b, rB=2b+1) and hides each problem's serial phase B under the OTHER
// problem's full-width matvec:
//   interval 1: all waves MV_A -> partA   ; wave1 runs phaseB_B(t-1) ; bar
//   interval 2: all waves MV_B -> partB   ; wave0 runs phaseB_A(t)   ; bar
// One barrier per problem-iteration (was 2) and the ~350-cyc wave-0-only
// phase-B window is absorbed into MV slack on a different wave. Per-problem
// arithmetic is R22-verbatim (owner-band-in-regs generalized to band 0/1;
// same values, same pk_add pairing) -> bit-exact, absmax must stay 0.
// Lessons enforced: no replication (R16/17/21/23), no flags (R19), no LDS
// atomics (R15), barriers beat polling (R19).
__global__ __launch_bounds__(512, 2) void k_pgd(
    const float* __restrict__ K, const float* __restrict__ alpha_init,
    double* __restrict__ neg_arr, double* __restrict__ sa_arr,
    int* __restrict__ cnt1, int* __restrict__ cntp, int* __restrict__ cnt0) {
  int rA = 2 * blockIdx.x;
  int rB = 2 * blockIdx.x + 1;
  int tid = threadIdx.x;
  int l = tid & 63;
  int rg = tid >> 6;        // 0..7 = row band (32 rows each)

  __shared__ __align__(16) float ytilA[BS], ytilB[BS];    // a-indexed y
  __shared__ __align__(16) float partA[8][BS];            // band 0 unused
  __shared__ __align__(16) float partB[8][BS];            // band 1 unused
  __shared__ float betat[1024];

  // beta table: betat[i] = i/(i+3) fp32 (read at index it+1)
  for (int i = tid; i < 1024; i += 512)
    betat[i] = (float)i / ((float)i + 3.0f);

  // stage K block (SHARED by both problems):
  // kq[16*k + j] = (K[32rg+2j][4l+k], K[32rg+2j+1][4l+k])
  v2f kq[64];
  #pragma unroll
  for (int j = 0; j < 16; ++j) {
    float4 r0 = *(const float4*)&K[(32 * rg + 2 * j + 0) * 512 + 4 * l];
    float4 r1 = *(const float4*)&K[(32 * rg + 2 * j + 1) * 512 + 4 * l];
    kq[j].x      = r0.x; kq[j].y      = r1.x;
    kq[16 + j].x = r0.y; kq[16 + j].y = r1.y;
    kq[32 + j].x = r0.z; kq[32 + j].y = r1.z;
    kq[48 + j].x = r0.w; kq[48 + j].y = r1.w;
  }
  #pragma unroll
  for (int j = 0; j < 64; ++j)
    asm volatile("" : "+v"(kq[j]));   // pin; block rematerialization

  // solver state: wave0 owns problem A, wave1 owns problem B (R15 lane
  // layout: lane l holds cols 4l..4l+3, dummy 0 at a==r)
  int myr = (rg == 1) ? rB : rA;     // meaningful on waves 0/1 only
  float al[4], ap[4], yv[4], kv[4], rm2[4];
  if (rg < 2) {
    #pragma unroll
    for (int k = 0; k < 4; ++k) {
      int a = 4 * l + k;
      if (a == myr) {
        al[k] = 0.f; ap[k] = 0.f; yv[k] = 0.f; kv[k] = 0.f; rm2[k] = 0.f;
      } else {
        int c = a - (a > myr ? 1 : 0);
        float v = alpha_init[myr * NN + c];
        v = fminf(fmaxf(v, 0.f), 1.f);
        al[k] = v; ap[k] = v; yv[k] = v;
        kv[k] = 1.0f - K[myr * 512 + a];
        rm2[k] = 2.0f;
      }
    }
    float4 y4 = {yv[0], yv[1], yv[2], yv[3]};
    if (rg == 0) *(float4*)&ytilA[4 * l] = y4;
    else         *(float4*)&ytilB[4 * l] = y4;
  }
  __syncthreads();                   // state + betat visible

  int rq = myr >> 2, rc = myr & 3;

  float qown[4];                     // owner wave's saved band partial

  // prologue: MV_A(0) fills partA (wave0 keeps band-0 partial in regs)
  {
    float4 accw = matvec8(kq, &ytilA[32 * rg]);
    if (rg != 0) *(float4*)&partA[rg][4 * l] = accw;
    else { qown[0] = accw.x; qown[1] = accw.y; qown[2] = accw.z; qown[3] = accw.w; }
  }
  __syncthreads();

  for (int it = 0; it < NUM_ITERS; ++it) {
    // ---- interval 2: MV_B(it) on all waves; wave0 does phaseB_A(it) ----
    {
      float4 accw = matvec8(kq, &ytilB[32 * rg]);
      if (rg != 1) *(float4*)&partB[rg][4 * l] = accw;
      else { qown[0] = accw.x; qown[1] = accw.y; qown[2] = accw.z; qown[3] = accw.w; }
      if (rg == 0) {
        float beta = betat[it + 1];
        phase_b<0>(partA, qown, al, ap, yv, kv, rm2, l, rq, rc, beta, ytilA);
      }
    }
    __syncthreads();   // partB + ytilA(it+1) visible

    // ---- interval 1': MV_A(it+1) on all waves; wave1 does phaseB_B(it) ----
    {
      float4 accw = matvec8(kq, &ytilA[32 * rg]);
      if (rg != 0) *(float4*)&partA[rg][4 * l] = accw;
      else { qown[0] = accw.x; qown[1] = accw.y; qown[2] = accw.z; qown[3] = accw.w; }
      if (rg == 1) {
        float beta = betat[it + 1];
        phase_b<1>(partB, qown, al, ap, yv, kv, rm2, l, rq, rc, beta, ytilB);
      }
    }
    __syncthreads();   // partA + ytilB(it+1) visible
  }

  // epilogue: wave0 holds problem-A state, wave1 problem-B — per-wave fp64
  // reductions (R22-exact), each writing its own r slot
  if (rg < 2) {
    int r = myr;
    double nl = 0.0, sa = 0.0;
    int c1 = 0, cp = 0, cz = 0;
    #pragma unroll
    for (int k = 0; k < 4; ++k) {
      int a = 4 * l + k;
      if (a != r) {
        float kx = K[a * 512 + 256 + r];     // KnT[r, c(a)]
        nl += (double)al[k] * (double)kx;
        sa += (double)al[k];
        c1 += (al[k] == 1.0f);
        cp += (al[k] > 0.0f);
        cz += (al[k] == 0.0f);
      }
    }
    nl = wred_d(nl); sa = wred_d(sa);
    c1 = wred_i(c1); cp = wred_i(cp); cz = wred_i(cz);
    if (l == 0) {
      neg_arr[r] = nl;
      sa_arr[r]  = sa;
      cnt1[r] = c1; cntp[r] = cp; cnt0[r] = cz;
    }
  }
}

// ---------------- kernel 4: final reduction to the 6 scalar outputs ----------------
__global__ void k_fin(const double* __restrict__ pk_knt, const double* __restrict__ pos_arr,
                      const double* __restrict__ neg_arr, const double* __restrict__ sa_arr,
                      const int* __restrict__ cnt1, const int* __restrict__ cntp,
                      const int* __restrict__ cnt0, float* __restrict__ out) {
  int t = threadIdx.x;  // 256
  __shared__ double rd[16];
  __shared__ int ri[12];
  double knt = pk_knt[t];
  double pos = pos_arr[t];
  double neg = neg_arr[t];
  double pl  = sa_arr[t] * pos_arr[t];
  int a1 = cnt1[t], ap = cntp[t], a0 = cnt0[t];
  knt = wred_d(knt); pos = wred_d(pos); neg = wred_d(neg); pl = wred_d(pl);
  a1 = wred_i(a1); ap = wred_i(ap); a0 = wred_i(a0);
  int w = t >> 6;
  if ((t & 63) == 0) {
    rd[w] = knt; rd[4 + w] = pos; rd[8 + w] = neg; rd[12 + w] = pl;
    ri[w] = a1; ri[4 + w] = ap; ri[8 + w] = a0;
  }
  __syncthreads();
  if (t == 0) {
    double kntS = rd[0] + rd[1] + rd[2] + rd[3];
    double posS = rd[4] + rd[5] + rd[6] + rd[7];
    double negS = rd[8] + rd[9] + rd[10] + rd[11];
    double plS  = rd[12] + rd[13] + rd[14] + rd[15];
    int c1t = ri[0] + ri[1] + ri[2] + ri[3];
    int cpt = ri[4] + ri[5] + ri[6] + ri[7];
    int c0t = ri[8] + ri[9] + ri[10] + ri[11];
    out[0] = (float)(negS / 256.0 - plS / 256.0);
    out[1] = (float)(posS / 256.0);
    out[2] = (float)(kntS / (256.0 * 255.0));
    out[3] = (float)c1t / ((float)cpt + 1e-10f);
    out[4] = (float)c0t / 65280.0f;
    out[5] = 0.0f;
  }
}

extern "C" void kernel_launch(void* const* d_in, const int* in_sizes, int n_in,
                              void* d_out, int out_size, void* d_ws, size_t ws_size,
                              hipStream_t stream) {
  const float* z     = (const float*)d_in[0];
  const float* ainit = (const float*)d_in[1];
  char* ws = (char*)d_ws;
  double* ftrT   = (double*)ws;                       // 512 KB
  float*  K      = (float*)(ws + 524288);             // 512 KB
  double* pk_knt = (double*)(ws + 1048576);
  double* pos_a  = (double*)(ws + 1048576 + 2048);
  double* neg_a  = (double*)(ws + 1048576 + 4096);
  double* sa_a   = (double*)(ws + 1048576 + 6144);
  int* cnt1 = (int*)(ws + 1048576 + 8192);
  int* cntp = (int*)(ws + 1048576 + 8192 + 1024);
  int* cnt0 = (int*)(ws + 1048576 + 8192 + 2048);
  float* out = (float*)d_out;

  k_ftr<<<256, 128, 0, stream>>>(z, ftrT);
  k_K  <<<256, 256, 0, stream>>>(ftrT, K, pk_knt, pos_a);
  k_pgd<<<128, 512, 0, stream>>>(K, ainit, neg_a, sa_a, cnt1, cntp, cnt0);
  k_fin<<<1, 256, 0, stream>>>(pk_knt, pos_a, neg_a, sa_a, cnt1, cntp, cnt0, out);
}

// Round 11
// 796.174 us; speedup vs baseline: 1.5665x; 1.5665x over previous
//
#include <hip/hip_runtime.h>
#include <math.h>

#define BS   256
#define NN   255
#define DIM  128
#define GAMMA 0.07
#define NUM_ITERS 1000

typedef float v2f __attribute__((ext_vector_type(2)));

__device__ __forceinline__ double wred_d(double v) {
  #pragma unroll
  for (int k = 1; k < 64; k <<= 1) v += __shfl_xor(v, k, 64);
  return v;
}
__device__ __forceinline__ int wred_i(int v) {
  #pragma unroll
  for (int k = 1; k < 64; k <<= 1) v += __shfl_xor(v, k, 64);
  return v;
}

// lane-uniform float readlane
__device__ __forceinline__ float RLF(float v, int lane) {
  return __int_as_float(__builtin_amdgcn_readlane(__float_as_int(v), lane));
}

// DPP wave64 sum -> total broadcast via readlane(63). VALU-only.
template <int CTRL, int RMASK>
__device__ __forceinline__ float dpp_add(float x) {
  int t = __builtin_amdgcn_update_dpp(0, __float_as_int(x), CTRL, RMASK, 0xf, true);
  return x + __int_as_float(t);
}
__device__ __forceinline__ float wred64_dpp(float x) {
  x = dpp_add<0x111, 0xf>(x);   // row_shr:1
  x = dpp_add<0x112, 0xf>(x);   // row_shr:2
  x = dpp_add<0x114, 0xf>(x);   // row_shr:4
  x = dpp_add<0x118, 0xf>(x);   // row_shr:8
  x = dpp_add<0x142, 0xa>(x);   // row_bcast:15
  x = dpp_add<0x143, 0xc>(x);   // row_bcast:31; lane63 = total
  return RLF(x, 63);
}

// fast reciprocal-sqrt: v_rsq_f32 + one Newton step (~0.5 ulp)
__device__ __forceinline__ float rsq_nr(float x) {
  float r;
  asm("v_rsq_f32 %0, %1" : "=v"(r) : "v"(x));
  r = r * (1.5f - 0.5f * x * r * r);
  return r;
}

// packed dual-fp32 FMA (VOP3P): acc.lo += k.lo*y.lo; acc.hi += k.hi*y.hi
__device__ __forceinline__ void pk_fma(v2f& acc, const v2f& k, const v2f& y) {
  asm("v_pk_fma_f32 %0, %1, %2, %0" : "+v"(acc) : "v"(k), "v"(y));
}

// packed dual-fp32 add (VOP3P): component-wise IEEE add == v_add_f32 per
// component -> bit-exact replacement for two scalar adds.
__device__ __forceinline__ v2f pk_add(v2f a, v2f b) {
  v2f d;
  asm("v_pk_add_f32 %0, %1, %2" : "=v"(d) : "v"(a), "v"(b));
  return d;
}

// ---------------- kernel 1: normalized features, stored transposed fp64 ----------------
__global__ void k_ftr(const float* __restrict__ z, double* __restrict__ ftrT) {
  int b = blockIdx.x;
  int d = threadIdx.x;
  double z0 = (double)z[b * 256 + d];
  double z1 = (double)z[b * 256 + 128 + d];
  double n = sqrt(z0 * z0 + z1 * z1);
  n = fmax(n, 1e-12);
  ftrT[d * 512 + b]       = z0 / n;
  ftrT[d * 512 + 256 + b] = z1 / n;
}

// ---------------- kernel 2: K = exp(-gamma * dist), fp64 math, fp32 store ----------------
__global__ void k_K(const double* __restrict__ ftrT, float* __restrict__ K,
                    double* __restrict__ pk_knt, double* __restrict__ pos_arr) {
  int i = blockIdx.x;
  int t = threadIdx.x;
  __shared__ double rowi[DIM];
  __shared__ double redd[4];
  if (t < DIM) rowi[t] = ftrT[t * 512 + i];
  __syncthreads();
  double xn = 0.0;
  #pragma unroll 8
  for (int d = 0; d < DIM; ++d) xn += rowi[d] * rowi[d];

  double knt_part = 0.0;
  #pragma unroll
  for (int h = 0; h < 2; ++h) {
    int j = t + h * 256;
    double dot = 0.0, sq = 0.0;
    #pragma unroll 8
    for (int d = 0; d < DIM; ++d) {
      double f = ftrT[d * 512 + j];
      dot += rowi[d] * f;
      sq  += f * f;
    }
    double dist = xn + sq - 2.0 * dot;
    double kv = exp(-GAMMA * dist);
    K[i * 512 + j] = (float)kv;
    if (h == 1) {
      if (j == 256 + i) pos_arr[i] = kv;
      else knt_part += kv;
    }
  }
  double w = wred_d(knt_part);
  if ((t & 63) == 0) redd[t >> 6] = w;
  __syncthreads();
  if (t == 0) pk_knt[i] = redd[0] + redd[1] + redd[2] + redd[3];
}

// ---------------- kernel 3: per-batch PGD — R22 (session best, 800 µs) ----------------
// R22 = R15 skeleton (2 barriers, wave-0-only phase B) + bit-exact chain
// micros: wave-0-local S (kills S_lds round trip), q0-in-registers (skips
// one part write+read), pk_add packed tree (28 adds -> 14, pairing kept).
// Full price list measured this session (all net-negative alternatives):
//   phase-B replication +130..+700 (R16/R17/R21/R23), flag sync +340 (R19),
//   2x occupancy +-0 (R18), butterfly-under-replication 0 net (R20/R21),
//   dual-problem pipeline +447 (R24: phase-B wave still runs its MV ->
//   chain unhidden, and grid 128 idles half the CUs).
// Structural floor (~1920 cyc/iter): MV issue 512/SIMD (FLOP-fixed, no fp32
// MFMA) + phase-B serial chain ~350 (algorithmic dependency) + barriers/LDS
// ~1000. Further gains require breaking bit-exactness (outputs count ==0.0
// and ==1.0 exactly -> ULP drift amplifies discretely). Stopping here.
__global__ __launch_bounds__(512, 2) void k_pgd(
    const float* __restrict__ K, const float* __restrict__ alpha_init,
    double* __restrict__ neg_arr, double* __restrict__ sa_arr,
    int* __restrict__ cnt1, int* __restrict__ cntp, int* __restrict__ cnt0) {
  int r = blockIdx.x;
  int tid = threadIdx.x;
  int l = tid & 63;
  int rg = tid >> 6;        // 0..7 = row band (32 rows each)

  __shared__ __align__(16) float ytil[BS];      // a-indexed, ytil[r]==0 always
  __shared__ __align__(16) float part[8][BS];   // [band][a-col] (row 0 unused)
  __shared__ float betat[1024];

  // beta table: betat[i] = i/(i+3) fp32 (read at index it+1)
  for (int i = tid; i < 1024; i += 512)
    betat[i] = (float)i / ((float)i + 3.0f);

  // stage K block as row-pair v2f: kq[16*k + j] = (K[32rg+2j][4l+k], K[32rg+2j+1][4l+k])
  v2f kq[64];
  #pragma unroll
  for (int j = 0; j < 16; ++j) {
    float4 r0 = *(const float4*)&K[(32 * rg + 2 * j + 0) * 512 + 4 * l];
    float4 r1 = *(const float4*)&K[(32 * rg + 2 * j + 1) * 512 + 4 * l];
    kq[j].x      = r0.x; kq[j].y      = r1.x;
    kq[16 + j].x = r0.y; kq[16 + j].y = r1.y;
    kq[32 + j].x = r0.z; kq[32 + j].y = r1.z;
    kq[48 + j].x = r0.w; kq[48 + j].y = r1.w;
  }
  #pragma unroll
  for (int j = 0; j < 64; ++j)
    asm volatile("" : "+v"(kq[j]));   // pin; block rematerialization

  // wave-0-only solver state: lane l holds a = 4l..4l+3 (dummy 0 at a==r)
  float al[4], ap[4], yv[4], kv[4], rm2[4];
  if (rg == 0) {
    #pragma unroll
    for (int k = 0; k < 4; ++k) {
      int a = 4 * l + k;
      if (a == r) {
        al[k] = 0.f; ap[k] = 0.f; yv[k] = 0.f; kv[k] = 0.f; rm2[k] = 0.f;
      } else {
        int c = a - (a > r ? 1 : 0);
        float v = alpha_init[r * NN + c];
        v = fminf(fmaxf(v, 0.f), 1.f);
        al[k] = v; ap[k] = v; yv[k] = v;
        kv[k] = 1.0f - K[r * 512 + a];
        rm2[k] = 2.0f;
      }
    }
    float4 y4 = {yv[0], yv[1], yv[2], yv[3]};
    *(float4*)&ytil[4 * l] = y4;     // a-indexed store (slot r holds 0)
  }
  __syncthreads();                   // state + betat visible

  int rq = r >> 2, rc = r & 3;       // location of column r in lane/comp grid

  for (int it = 0; it < NUM_ITERS; ++it) {
    float beta;
    if (rg == 0) beta = betat[it + 1];         // hoisted above B1

    // ---- phase A (all 8 waves): band matvec ----
    const float4* yb = (const float4*)&ytil[32 * rg];
    v2f a0 = {0.f, 0.f}, a1 = {0.f, 0.f}, a2 = {0.f, 0.f}, a3 = {0.f, 0.f};
    #pragma unroll
    for (int jj = 0; jj < 8; ++jj) {
      float4 yq = yb[jj];                      // wave-broadcast b128 (4 rows of y)
      v2f ylo = {yq.x, yq.y};
      v2f yhi = {yq.z, yq.w};
      pk_fma(a0, kq[2 * jj],      ylo); pk_fma(a0, kq[2 * jj + 1],      yhi);
      pk_fma(a1, kq[16 + 2 * jj], ylo); pk_fma(a1, kq[16 + 2 * jj + 1], yhi);
      pk_fma(a2, kq[32 + 2 * jj], ylo); pk_fma(a2, kq[32 + 2 * jj + 1], yhi);
      pk_fma(a3, kq[48 + 2 * jj], ylo); pk_fma(a3, kq[48 + 2 * jj + 1], yhi);
    }
    float4 accw = {a0.x + a0.y, a1.x + a1.y, a2.x + a2.y, a3.x + a3.y};

    float Sv;
    if (rg != 0) {
      *(float4*)&part[rg][4 * l] = accw;       // conflict-free b128 write
    } else {
      // wave-0-local S: same inputs (ytil[4l]==yv) + same tree as the old
      // wave-1 path -> bit-exact. Issued while producers drain to B1.
      Sv = wred64_dpp((yv[0] + yv[1]) + (yv[2] + yv[3]));
    }
    __syncthreads();                           // B1: partials visible

    // ---- phase B: region2 on wave 0 only ----
    if (rg == 0) {
      // q0 = own band partial (registers; same bits as the old LDS round trip)
      v2f q0l = {accw.x, accw.y}, q0h = {accw.z, accw.w};
      float4 q1 = *(const float4*)&part[1][4 * l];
      float4 q2 = *(const float4*)&part[2][4 * l];
      float4 q3 = *(const float4*)&part[3][4 * l];
      float4 q4 = *(const float4*)&part[4][4 * l];
      float4 q5 = *(const float4*)&part[5][4 * l];
      float4 q6 = *(const float4*)&part[6][4 * l];
      float4 q7 = *(const float4*)&part[7][4 * l];
      // pk-packed pairwise tree: identical pairing/order as R15's add4 tree
      v2f s01l = pk_add(q0l, (v2f){q1.x, q1.y});
      v2f s01h = pk_add(q0h, (v2f){q1.z, q1.w});
      v2f s23l = pk_add((v2f){q2.x, q2.y}, (v2f){q3.x, q3.y});
      v2f s23h = pk_add((v2f){q2.z, q2.w}, (v2f){q3.z, q3.w});
      v2f s45l = pk_add((v2f){q4.x, q4.y}, (v2f){q5.x, q5.y});
      v2f s45h = pk_add((v2f){q4.z, q4.w}, (v2f){q5.z, q5.w});
      v2f s67l = pk_add((v2f){q6.x, q6.y}, (v2f){q7.x, q7.y});
      v2f s67h = pk_add((v2f){q6.z, q6.w}, (v2f){q7.z, q7.w});
      v2f sAl = pk_add(s01l, s23l);
      v2f sAh = pk_add(s01h, s23h);
      v2f sBl = pk_add(s45l, s67l);
      v2f sBh = pk_add(s45h, s67h);
      v2f gAl = pk_add(sAl, sBl);
      v2f gAh = pk_add(sAh, sBh);
      float4 gA = {gAl.x, gAl.y, gAh.x, gAh.y};
      // gr = gA at column r (uniform rc select + readlane)
      float grv = (rc == 0) ? gA.x : (rc == 1) ? gA.y : (rc == 2) ? gA.z : gA.w;
      float gr = RLF(grv, rq);
      // a==r col: kv=rm2=yv=0 and gA==gr -> g = 0 exactly
      float g[4];
      g[0] = (gA.x - gr) - rm2[0] + kv[0] * Sv + 0.1f * yv[0];
      g[1] = (gA.y - gr) - rm2[1] + kv[1] * Sv + 0.1f * yv[1];
      g[2] = (gA.z - gr) - rm2[2] + kv[2] * Sv + 0.1f * yv[2];
      g[3] = (gA.w - gr) - rm2[3] + kv[3] * Sv + 0.1f * yv[3];
      float n2 = wred64_dpp((g[0] * g[0] + g[1] * g[1]) + (g[2] * g[2] + g[3] * g[3]));
      float sinv = 0.001f * rsq_nr(n2);
      #pragma unroll
      for (int k = 0; k < 4; ++k) {
        float na = fminf(fmaxf(fmaf(-sinv, g[k], yv[k]), 0.f), 1.f);
        ap[k] = al[k];
        al[k] = na;
        yv[k] = fmaf(beta, na - ap[k], na);
      }
      float4 y4 = {yv[0], yv[1], yv[2], yv[3]};
      *(float4*)&ytil[4 * l] = y4;             // one b128, conflict-free
    }
    __syncthreads();                           // B2: ytil ready
  }

  // epilogue: wave 0 holds the state — single-wave fp64 reductions
  if (rg == 0) {
    double nl = 0.0, sa = 0.0;
    int c1 = 0, cp = 0, cz = 0;
    #pragma unroll
    for (int k = 0; k < 4; ++k) {
      int a = 4 * l + k;
      if (a != r) {
        float kx = K[a * 512 + 256 + r];     // KnT[r, c(a)]
        nl += (double)al[k] * (double)kx;
        sa += (double)al[k];
        c1 += (al[k] == 1.0f);
        cp += (al[k] > 0.0f);
        cz += (al[k] == 0.0f);
      }
    }
    nl = wred_d(nl); sa = wred_d(sa);
    c1 = wred_i(c1); cp = wred_i(cp); cz = wred_i(cz);
    if (l == 0) {
      neg_arr[r] = nl;
      sa_arr[r]  = sa;
      cnt1[r] = c1; cntp[r] = cp; cnt0[r] = cz;
    }
  }
}

// ---------------- kernel 4: final reduction to the 6 scalar outputs ----------------
__global__ void k_fin(const double* __restrict__ pk_knt, const double* __restrict__ pos_arr,
                      const double* __restrict__ neg_arr, const double* __restrict__ sa_arr,
                      const int* __restrict__ cnt1, const int* __restrict__ cntp,
                      const int* __restrict__ cnt0, float* __restrict__ out) {
  int t = threadIdx.x;  // 256
  __shared__ double rd[16];
  __shared__ int ri[12];
  double knt = pk_knt[t];
  double pos = pos_arr[t];
  double neg = neg_arr[t];
  double pl  = sa_arr[t] * pos_arr[t];
  int a1 = cnt1[t], ap = cntp[t], a0 = cnt0[t];
  knt = wred_d(knt); pos = wred_d(pos); neg = wred_d(neg); pl = wred_d(pl);
  a1 = wred_i(a1); ap = wred_i(ap); a0 = wred_i(a0);
  int w = t >> 6;
  if ((t & 63) == 0) {
    rd[w] = knt; rd[4 + w] = pos; rd[8 + w] = neg; rd[12 + w] = pl;
    ri[w] = a1; ri[4 + w] = ap; ri[8 + w] = a0;
  }
  __syncthreads();
  if (t == 0) {
    double kntS = rd[0] + rd[1] + rd[2] + rd[3];
    double posS = rd[4] + rd[5] + rd[6] + rd[7];
    double negS = rd[8] + rd[9] + rd[10] + rd[11];
    double plS  = rd[12] + rd[13] + rd[14] + rd[15];
    int c1t = ri[0] + ri[1] + ri[2] + ri[3];
    int cpt = ri[4] + ri[5] + ri[6] + ri[7];
    int c0t = ri[8] + ri[9] + ri[10] + ri[11];
    out[0] = (float)(negS / 256.0 - plS / 256.0);
    out[1] = (float)(posS / 256.0);
    out[2] = (float)(kntS / (256.0 * 255.0));
    out[3] = (float)c1t / ((float)cpt + 1e-10f);
    out[4] = (float)c0t / 65280.0f;
    out[5] = 0.0f;
  }
}

extern "C" void kernel_launch(void* const* d_in, const int* in_sizes, int n_in,
                              void* d_out, int out_size, void* d_ws, size_t ws_size,
                              hipStream_t stream) {
  const float* z     = (const float*)d_in[0];
  const float* ainit = (const float*)d_in[1];
  char* ws = (char*)d_ws;
  double* ftrT   = (double*)ws;                       // 512 KB
  float*  K      = (float*)(ws + 524288);             // 512 KB
  double* pk_knt = (double*)(ws + 1048576);
  double* pos_a  = (double*)(ws + 1048576 + 2048);
  double* neg_a  = (double*)(ws + 1048576 + 4096);
  double* sa_a   = (double*)(ws + 1048576 + 6144);
  int* cnt1 = (int*)(ws + 1048576 + 8192);
  int* cntp = (int*)(ws + 1048576 + 8192 + 1024);
  int* cnt0 = (int*)(ws + 1048576 + 8192 + 2048);
  float* out = (float*)d_out;

  k_ftr<<<256, 128, 0, stream>>>(z, ftrT);
  k_K  <<<256, 256, 0, stream>>>(ftrT, K, pk_knt, pos_a);
  k_pgd<<<256, 512, 0, stream>>>(K, ainit, neg_a, sa_a, cnt1, cntp, cnt0);
  k_fin<<<1, 256, 0, stream>>>(pk_knt, pos_a, neg_a, sa_a, cnt1, cntp, cnt0, out);
}